// Round 12
// baseline (317.048 us; speedup 1.0000x reference)
//
#include <hip/hip_runtime.h>
#include <math.h>

// B=16, H=12, S=1024, D=64.  BH=192, rows = B*H*S = 196608.
// R12: BARRIER-FREE, LDS-FREE main loop.
//   R11 post-mortem: prefetch restored but attn stuck ~97us; every LDS-staged
//   variant shows the same signature (MfmaUtil<28, VALU<52, conflicts 5-10M,
//   8-way bank groups from the PAD=72 fragment pattern).  K/V per bh = 256KB
//   = L2-resident (same-bh blocks share an XCD: 192 % 8 == 0).  Guide
//   "common mistake #7": at S=1024, K/V LDS staging is pure overhead.
//   - main loop: each wave loads K fragments (ka[4][2], 32 regs) and V
//     fragments (per-half, 16 regs) DIRECTLY from gk/gvt.  No LDS, no
//     barriers, no staging writes; 8 waves/block fully decoupled, 16
//     waves/CU of independent streams hide load latency.
//   - prologue (x stage + Q-proj roundtrip) unchanged; xq LDS used only there.
// ws layout (bf16): K[NE] | Vt_perm[NE]   (50.3 MB)
//
// KEY-PERMUTATION TRICK (unchanged): P^T exits QK in C-layout; reinterpreted
// as a B-fragment it supplies key kappa(s) at MFMA k-slot s.  Vt and Wo are
// stored/loaded pre-permuted by kappa so P and O feed MFMA from registers.
// kappa: s = 16t + 4q + r  ->  32*(t>>1) + 8*q + 4*(t&1) + r.

typedef __bf16 bf16x8 __attribute__((ext_vector_type(8)));
typedef float  f32x4  __attribute__((ext_vector_type(4)));

#define MFMA(a, b, c) __builtin_amdgcn_mfma_f32_16x16x32_bf16((a), (b), (c), 0, 0, 0)

static constexpr int S = 1024;
static constexpr int PAD = 72;      // 144 B row stride: 16B-aligned, breaks 128B aliasing
static constexpr size_t NE = 196608ull * 64ull;
// Q prescale: 1/sqrt(64) * log2(e)  -> scores arrive pre-scaled for exp2
static constexpr float QSCALE = 0.125f * 1.4426950408889634f;

__device__ inline unsigned long long pack4bf(float a, float b, float c, float d) {
    union { __bf16 h[4]; unsigned long long u; } pk;
    pk.h[0] = (__bf16)a; pk.h[1] = (__bf16)b; pk.h[2] = (__bf16)c; pk.h[3] = (__bf16)d;
    return pk.u;
}

union frag_u { bf16x8 v; unsigned long long u[2]; };

// ---------------------------------------------------------------------------
// Kernel 0: K/Vt projection (verbatim R11).  K row-major; Vt [bh][d][key-kappa].
// LDS = lx 18.4K + lbuf 18.4K + lw 8K + lb 0.5K = 45.3 KB -> 3 blocks/CU.
// ---------------------------------------------------------------------------
__global__ __launch_bounds__(256, 3) void projkv(
    const float* __restrict__ x,
    const float* __restrict__ Wk, const float* __restrict__ bk,
    const float* __restrict__ Wv, const float* __restrict__ bv,
    __bf16* __restrict__ gk, __bf16* __restrict__ gvt)
{
    __shared__ __align__(16) __bf16 lx[128][PAD];
    __shared__ __align__(16) __bf16 lbuf[128][PAD];   // roundtrip; reused as [64][136] for Vt
    __shared__ __align__(16) __bf16 lw[2][8][64][8];
    __shared__ float lb[2][64];

    const int tid = threadIdx.x;
    const int row_base = blockIdx.x * 128;

    #pragma unroll
    for (int i = tid * 4; i < 8192; i += 1024) {
        float4 v = *(const float4*)(x + (size_t)row_base * 64 + i);
        int r = i >> 6, c = i & 63;
        *(unsigned long long*)&lx[r][c] = pack4bf(v.x, v.y, v.z, v.w);
    }
    #pragma unroll
    for (int c = tid; c < 1024; c += 256) {
        int mtx = c >> 9, rest = c & 511;
        int fe = rest >> 6, ln = rest & 63;
        int mm = ln & 15, qq = ln >> 4;
        int et = fe >> 1, half = fe & 1;
        const float* src = (mtx ? Wv : Wk) + (size_t)(et * 16 + mm) * 64 + half * 32 + qq * 8;
        float4 u0 = *(const float4*)(src);
        float4 u1 = *(const float4*)(src + 4);
        *(unsigned long long*)&lw[mtx][fe][ln][0] = pack4bf(u0.x, u0.y, u0.z, u0.w);
        *(unsigned long long*)&lw[mtx][fe][ln][4] = pack4bf(u1.x, u1.y, u1.z, u1.w);
    }
    if (tid < 64) { lb[0][tid] = bk[tid]; lb[1][tid] = bv[tid]; }
    __syncthreads();

    const int w = tid >> 6, lane = tid & 63, m = lane & 15, quad = lane >> 4;
    const int bh = row_base >> 10;
    const int s_base = row_base & 1023;

    bf16x8 xf[2][2];
    #pragma unroll
    for (int g = 0; g < 2; g++) {
        xf[g][0] = *(const bf16x8*)&lx[w * 32 + g * 16 + m][quad * 8];
        xf[g][1] = *(const bf16x8*)&lx[w * 32 + g * 16 + m][32 + quad * 8];
    }

    #pragma unroll
    for (int et = 0; et < 4; et++) {
        bf16x8 wf0 = *(const bf16x8*)&lw[0][et * 2 + 0][lane][0];
        bf16x8 wf1 = *(const bf16x8*)&lw[0][et * 2 + 1][lane][0];
        float4 bias = *(const float4*)&lb[0][et * 16 + quad * 4];
        #pragma unroll
        for (int g = 0; g < 2; g++) {
            f32x4 acc = {0.f, 0.f, 0.f, 0.f};
            acc = MFMA(wf0, xf[g][0], acc);
            acc = MFMA(wf1, xf[g][1], acc);
            *(unsigned long long*)&lbuf[w * 32 + g * 16 + m][et * 16 + quad * 4] =
                pack4bf(acc[0] + bias.x, acc[1] + bias.y,
                        acc[2] + bias.z, acc[3] + bias.w);
        }
    }
    __syncthreads();
    #pragma unroll
    for (int it = 0; it < 4; it++) {
        int idx = it * 256 + tid;
        int row = idx >> 3, col = (idx & 7) * 8;
        *(uint4*)(gk + ((size_t)row_base + row) * 64 + col) = *(uint4*)&lbuf[row][col];
    }
    __syncthreads();

    __bf16 (*lvt)[136] = (__bf16(*)[136])&lbuf[0][0];
    #pragma unroll
    for (int et = 0; et < 4; et++) {
        bf16x8 wf0 = *(const bf16x8*)&lw[1][et * 2 + 0][lane][0];
        bf16x8 wf1 = *(const bf16x8*)&lw[1][et * 2 + 1][lane][0];
        const float bias = lb[1][et * 16 + m];
        #pragma unroll
        for (int g = 0; g < 2; g++) {
            f32x4 acc = {0.f, 0.f, 0.f, 0.f};
            acc = MFMA(xf[g][0], wf0, acc);
            acc = MFMA(xf[g][1], wf1, acc);
            const int tp = (2 * w + g) & 3;
            const int p0 = 64 * (w >> 1) + 32 * (tp >> 1) + 8 * quad + 4 * (tp & 1);
            *(unsigned long long*)&lvt[et * 16 + m][p0] =
                pack4bf(acc[0] + bias, acc[1] + bias, acc[2] + bias, acc[3] + bias);
        }
    }
    __syncthreads();
    #pragma unroll
    for (int it = 0; it < 4; it++) {
        int idx = it * 256 + tid;
        int row = idx >> 4, col = (idx & 15) * 8;
        *(uint4*)(gvt + ((size_t)bh * 64 + row) * 1024 + s_base + col) = *(uint4*)&lvt[row][col];
    }
}

// ---------------------------------------------------------------------------
// Kernel 1: Q-proj prologue + flash attention + fused output projection.
// Grid (192 bh, 4 qb) x 512 threads (8 waves, 32 q-rows each).
// Main loop: K/V fragments straight from global (L2-hot), ZERO LDS/barriers.
// ---------------------------------------------------------------------------
__global__ __launch_bounds__(512, 4) void attn(
    const float* __restrict__ x,
    const float* __restrict__ Wq, const float* __restrict__ bq,
    const __bf16* __restrict__ gk, const __bf16* __restrict__ gvt,
    const float* __restrict__ Wo, const float* __restrict__ bo,
    float* __restrict__ out)
{
    __shared__ __align__(16) __bf16 xq[256][PAD];   // prologue only

    const int tid = threadIdx.x;
    const int w = tid >> 6, lane = tid & 63, m = lane & 15, quad = lane >> 4;
    const int bh = blockIdx.x;
    const int q0 = blockIdx.y * 256 + w * 32;

    // ---- prologue: stage my 256 x-rows fp32 -> bf16 ----
    const float* xq32 = x + ((size_t)bh * 1024 + blockIdx.y * 256) * 64;
    #pragma unroll
    for (int i = tid * 4; i < 16384; i += 2048) {
        float4 v = *(const float4*)(xq32 + i);
        int r = i >> 6, c = i & 63;
        *(unsigned long long*)&xq[r][c] = pack4bf(v.x, v.y, v.z, v.w);
    }
    __syncthreads();

    // Q-proj: this wave's 32 rows only (wave-private reads/writes)
    bf16x8 xqf[2][2];
    #pragma unroll
    for (int g = 0; g < 2; g++) {
        xqf[g][0] = *(const bf16x8*)&xq[w * 32 + g * 16 + m][quad * 8];
        xqf[g][1] = *(const bf16x8*)&xq[w * 32 + g * 16 + m][32 + quad * 8];
    }
    #pragma unroll
    for (int et = 0; et < 4; et++) {
        const float* wqrow = Wq + (size_t)(et * 16 + m) * 64;
        float4 a0 = *(const float4*)(wqrow + quad * 8);
        float4 a1 = *(const float4*)(wqrow + quad * 8 + 4);
        float4 a2 = *(const float4*)(wqrow + 32 + quad * 8);
        float4 a3 = *(const float4*)(wqrow + 36 + quad * 8);
        frag_u wf0, wf1;
        wf0.u[0] = pack4bf(a0.x, a0.y, a0.z, a0.w);
        wf0.u[1] = pack4bf(a1.x, a1.y, a1.z, a1.w);
        wf1.u[0] = pack4bf(a2.x, a2.y, a2.z, a2.w);
        wf1.u[1] = pack4bf(a3.x, a3.y, a3.z, a3.w);
        float4 bias = *(const float4*)(bq + et * 16 + quad * 4);
        #pragma unroll
        for (int g = 0; g < 2; g++) {
            f32x4 acc = {0.f, 0.f, 0.f, 0.f};
            acc = MFMA(wf0.v, xqf[g][0], acc);
            acc = MFMA(wf1.v, xqf[g][1], acc);
            *(unsigned long long*)&xq[w * 32 + g * 16 + m][et * 16 + quad * 4] =
                pack4bf((acc[0] + bias.x) * QSCALE, (acc[1] + bias.y) * QSCALE,
                        (acc[2] + bias.z) * QSCALE, (acc[3] + bias.w) * QSCALE);
        }
    }
    bf16x8 qf[2][2];
    #pragma unroll
    for (int g = 0; g < 2; g++) {
        qf[g][0] = *(const bf16x8*)&xq[w * 32 + g * 16 + m][quad * 8];
        qf[g][1] = *(const bf16x8*)&xq[w * 32 + g * 16 + m][32 + quad * 8];
    }
    // no further barriers: main loop touches no LDS.

    f32x4 o[2][4];
    float lsum[2] = {0.f, 0.f};
    #pragma unroll
    for (int g = 0; g < 2; g++)
        #pragma unroll
        for (int n = 0; n < 4; n++) o[g][n] = {0.f, 0.f, 0.f, 0.f};

    const __bf16* kbase = gk + (size_t)bh * S * 64;
    const __bf16* vbase = gvt + (size_t)bh * 64 * 1024;

    for (int kb = 0; kb < 16; kb++) {
        // ---- K fragments straight from global (L2-hot, 8 x 16B per lane) ----
        bf16x8 ka[4][2];
        #pragma unroll
        for (int t = 0; t < 4; t++) {
            const __bf16* kr = kbase + (size_t)(kb * 64 + t * 16 + m) * 64;
            ka[t][0] = *(const bf16x8*)(kr + quad * 8);
            ka[t][1] = *(const bf16x8*)(kr + 32 + quad * 8);
        }

        // ---- QK -> exp2 -> pack P^T straight into B-fragments ----
        __builtin_amdgcn_s_setprio(1);
        frag_u pb[2][2];
        #pragma unroll
        for (int t = 0; t < 4; t++) {
            #pragma unroll
            for (int g = 0; g < 2; g++) {
                f32x4 acc = {0.f, 0.f, 0.f, 0.f};
                acc = MFMA(ka[t][0], qf[g][0], acc);
                acc = MFMA(ka[t][1], qf[g][1], acc);
                float e0 = __builtin_amdgcn_exp2f(acc[0]);
                float e1 = __builtin_amdgcn_exp2f(acc[1]);
                float e2 = __builtin_amdgcn_exp2f(acc[2]);
                float e3 = __builtin_amdgcn_exp2f(acc[3]);
                lsum[g] += (e0 + e1) + (e2 + e3);
                pb[g][t >> 1].u[t & 1] = pack4bf(e0, e1, e2, e3);
            }
        }
        __builtin_amdgcn_s_setprio(0);

        // ---- PV in two halves (V fragments straight from global) ----
        #pragma unroll
        for (int nh = 0; nh < 2; nh++) {
            bf16x8 va[2][2];
            #pragma unroll
            for (int n2 = 0; n2 < 2; n2++) {
                const int n = nh * 2 + n2;
                const __bf16* vr = vbase + (size_t)(n * 16 + m) * 1024 + kb * 64;
                va[n2][0] = *(const bf16x8*)(vr + quad * 8);
                va[n2][1] = *(const bf16x8*)(vr + 32 + quad * 8);
            }
            __builtin_amdgcn_s_setprio(1);
            #pragma unroll
            for (int n2 = 0; n2 < 2; n2++) {
                const int n = nh * 2 + n2;
                #pragma unroll
                for (int g = 0; g < 2; g++) {
                    o[g][n] = MFMA(va[n2][0], pb[g][0].v, o[g][n]);
                    o[g][n] = MFMA(va[n2][1], pb[g][1].v, o[g][n]);
                }
            }
            __builtin_amdgcn_s_setprio(0);
        }
    }

    // ---- epilogue: l reduce, O^T regs -> A-fragments, fused @ Wo + bo ----
    #pragma unroll
    for (int g = 0; g < 2; g++) {
        lsum[g] += __shfl_xor(lsum[g], 16);
        lsum[g] += __shfl_xor(lsum[g], 32);
    }

    // Wo fragments built inline from fp32 with kappa folded into addresses:
    bf16x8 wf[4][2];
    #pragma unroll
    for (int et = 0; et < 4; et++) {
        const float* worow = Wo + (size_t)(et * 16 + m) * 64;
        float4 c0 = *(const float4*)(worow + 4 * quad);
        float4 c1 = *(const float4*)(worow + 16 + 4 * quad);
        float4 c2 = *(const float4*)(worow + 32 + 4 * quad);
        float4 c3 = *(const float4*)(worow + 48 + 4 * quad);
        frag_u f0, f1;
        f0.u[0] = pack4bf(c0.x, c0.y, c0.z, c0.w);
        f0.u[1] = pack4bf(c1.x, c1.y, c1.z, c1.w);
        f1.u[0] = pack4bf(c2.x, c2.y, c2.z, c2.w);
        f1.u[1] = pack4bf(c3.x, c3.y, c3.z, c3.w);
        wf[et][0] = f0.v;
        wf[et][1] = f1.v;
    }
    float biasr[4];
    #pragma unroll
    for (int et = 0; et < 4; et++) biasr[et] = bo[et * 16 + m];

    #pragma unroll
    for (int g = 0; g < 2; g++) {
        const float inv = 1.f / lsum[g];
        frag_u af0, af1;
        af0.u[0] = pack4bf(o[g][0][0] * inv, o[g][0][1] * inv, o[g][0][2] * inv, o[g][0][3] * inv);
        af0.u[1] = pack4bf(o[g][1][0] * inv, o[g][1][1] * inv, o[g][1][2] * inv, o[g][1][3] * inv);
        af1.u[0] = pack4bf(o[g][2][0] * inv, o[g][2][1] * inv, o[g][2][2] * inv, o[g][2][3] * inv);
        af1.u[1] = pack4bf(o[g][3][0] * inv, o[g][3][1] * inv, o[g][3][2] * inv, o[g][3][3] * inv);
        #pragma unroll
        for (int et = 0; et < 4; et++) {
            f32x4 acc = {0.f, 0.f, 0.f, 0.f};
            acc = MFMA(af0.v, wf[et][0], acc);
            acc = MFMA(af1.v, wf[et][1], acc);
            #pragma unroll
            for (int r = 0; r < 4; r++) {
                size_t row = (size_t)bh * S + q0 + g * 16 + quad * 4 + r;
                out[row * 64 + et * 16 + m] = acc[r] + biasr[et];
            }
        }
    }
}

// ---------------------------------------------------------------------------
extern "C" void kernel_launch(void* const* d_in, const int* in_sizes, int n_in,
                              void* d_out, int out_size, void* d_ws, size_t ws_size,
                              hipStream_t stream) {
    const float* x  = (const float*)d_in[0];
    const float* Wq = (const float*)d_in[1];
    const float* bq = (const float*)d_in[2];
    const float* Wk = (const float*)d_in[3];
    const float* bk = (const float*)d_in[4];
    const float* Wv = (const float*)d_in[5];
    const float* bv = (const float*)d_in[6];
    const float* Wo = (const float*)d_in[7];
    const float* bo = (const float*)d_in[8];
    float* out = (float*)d_out;

    __bf16* gk  = (__bf16*)d_ws;
    __bf16* gvt = gk + NE;

    projkv<<<1536, 256, 0, stream>>>(x, Wk, bk, Wv, bv, gk, gvt);
    attn<<<dim3(192, 4), 512, 0, stream>>>(x, Wq, bq, gk, gvt, Wo, bo, out);
}

// Round 13
// 222.334 us; speedup vs baseline: 1.4260x; 1.4260x over previous
//
#include <hip/hip_runtime.h>
#include <math.h>

// B=16, H=12, S=1024, D=64.  BH=192, rows = B*H*S = 196608.
// R13: barrier-free main loop with FRAGMENT-MAJOR K/V workspace.
//   R12 post-mortem: LDS-free loop was right, addresses were wrong -- K-frag
//   loads strided 128B/lane (16 lines/instr), V-frag 2KB/lane (64 lines/instr)
//   -> L2 transaction amplification, 213us.  R11 post-mortem: LDS variants
//   lose ~4cyc/read to the PAD=72 8-bank pattern (6.7M conflicts).
//   Fix: projkv stores K and Vt in fragment-major order
//     gk[bh][kb][f=t*2+half][lane][8], gvt[bh][kb][f=n*2+half][lane][8]
//   (same bytes, permuted addresses; stores stay coalesced uint4).  attn
//   loads each MFMA fragment as ONE contiguous 1KB wave transaction
//   (base + f*512 + lane*8), L2-broadcast across the 8 waves x 4 blocks
//   sharing a bh.  Main loop: no LDS, no barriers, no conflicts; all 16
//   loads issued at top of each kb so V latency hides under QK.
// ws layout (bf16): Kfrag[NE] | Vtfrag[NE]   (50.3 MB)
//
// KEY-PERMUTATION TRICK (unchanged): P^T exits QK in C-layout; reinterpreted
// as a B-fragment it supplies key kappa(s) at MFMA k-slot s.  Vt and Wo are
// stored/loaded pre-permuted by kappa so P and O feed MFMA from registers.
// kappa: s = 16t + 4q + r  ->  32*(t>>1) + 8*q + 4*(t&1) + r.

typedef __bf16 bf16x8 __attribute__((ext_vector_type(8)));
typedef float  f32x4  __attribute__((ext_vector_type(4)));

#define MFMA(a, b, c) __builtin_amdgcn_mfma_f32_16x16x32_bf16((a), (b), (c), 0, 0, 0)

static constexpr int S = 1024;
static constexpr int PAD = 72;      // 144 B row stride (proj kernel only)
static constexpr size_t NE = 196608ull * 64ull;
// Q prescale: 1/sqrt(64) * log2(e)  -> scores arrive pre-scaled for exp2
static constexpr float QSCALE = 0.125f * 1.4426950408889634f;

__device__ inline unsigned long long pack4bf(float a, float b, float c, float d) {
    union { __bf16 h[4]; unsigned long long u; } pk;
    pk.h[0] = (__bf16)a; pk.h[1] = (__bf16)b; pk.h[2] = (__bf16)c; pk.h[3] = (__bf16)d;
    return pk.u;
}

union frag_u { bf16x8 v; unsigned long long u[2]; };

// ---------------------------------------------------------------------------
// Kernel 0: K/Vt projection, fragment-major stores.
// Per bh: 16 kb-tiles x 8 frags x 64 lanes x 8 elems = 65536 elems.
// LDS = lx 18.4K + lbuf 18.4K + lw 8K + lb 0.5K = 45.3 KB -> 3 blocks/CU.
// ---------------------------------------------------------------------------
__global__ __launch_bounds__(256, 3) void projkv(
    const float* __restrict__ x,
    const float* __restrict__ Wk, const float* __restrict__ bk,
    const float* __restrict__ Wv, const float* __restrict__ bv,
    __bf16* __restrict__ gk, __bf16* __restrict__ gvt)
{
    __shared__ __align__(16) __bf16 lx[128][PAD];
    __shared__ __align__(16) __bf16 lbuf[128][PAD];   // roundtrip; reused as [64][136] for Vt
    __shared__ __align__(16) __bf16 lw[2][8][64][8];
    __shared__ float lb[2][64];

    const int tid = threadIdx.x;
    const int row_base = blockIdx.x * 128;

    #pragma unroll
    for (int i = tid * 4; i < 8192; i += 1024) {
        float4 v = *(const float4*)(x + (size_t)row_base * 64 + i);
        int r = i >> 6, c = i & 63;
        *(unsigned long long*)&lx[r][c] = pack4bf(v.x, v.y, v.z, v.w);
    }
    #pragma unroll
    for (int c = tid; c < 1024; c += 256) {
        int mtx = c >> 9, rest = c & 511;
        int fe = rest >> 6, ln = rest & 63;
        int mm = ln & 15, qq = ln >> 4;
        int et = fe >> 1, half = fe & 1;
        const float* src = (mtx ? Wv : Wk) + (size_t)(et * 16 + mm) * 64 + half * 32 + qq * 8;
        float4 u0 = *(const float4*)(src);
        float4 u1 = *(const float4*)(src + 4);
        *(unsigned long long*)&lw[mtx][fe][ln][0] = pack4bf(u0.x, u0.y, u0.z, u0.w);
        *(unsigned long long*)&lw[mtx][fe][ln][4] = pack4bf(u1.x, u1.y, u1.z, u1.w);
    }
    if (tid < 64) { lb[0][tid] = bk[tid]; lb[1][tid] = bv[tid]; }
    __syncthreads();

    const int w = tid >> 6, lane = tid & 63, m = lane & 15, quad = lane >> 4;
    const int bh = row_base >> 10;
    const int s_base = row_base & 1023;
    const int kb0 = s_base >> 6;                      // first of 2 kb tiles

    bf16x8 xf[2][2];
    #pragma unroll
    for (int g = 0; g < 2; g++) {
        xf[g][0] = *(const bf16x8*)&lx[w * 32 + g * 16 + m][quad * 8];
        xf[g][1] = *(const bf16x8*)&lx[w * 32 + g * 16 + m][32 + quad * 8];
    }

    // ---- K: compute into lbuf (row-major), then fragment-major store ----
    #pragma unroll
    for (int et = 0; et < 4; et++) {
        bf16x8 wf0 = *(const bf16x8*)&lw[0][et * 2 + 0][lane][0];
        bf16x8 wf1 = *(const bf16x8*)&lw[0][et * 2 + 1][lane][0];
        float4 bias = *(const float4*)&lb[0][et * 16 + quad * 4];
        #pragma unroll
        for (int g = 0; g < 2; g++) {
            f32x4 acc = {0.f, 0.f, 0.f, 0.f};
            acc = MFMA(wf0, xf[g][0], acc);
            acc = MFMA(wf1, xf[g][1], acc);
            *(unsigned long long*)&lbuf[w * 32 + g * 16 + m][et * 16 + quad * 4] =
                pack4bf(acc[0] + bias.x, acc[1] + bias.y,
                        acc[2] + bias.z, acc[3] + bias.w);
        }
    }
    __syncthreads();
    #pragma unroll
    for (int it = 0; it < 4; it++) {
        int c = it * 256 + tid;                       // chunk in [0,1024)
        int kbl = c >> 9, f = (c >> 6) & 7, ln = c & 63;
        int t = f >> 1, half = f & 1;
        int row = kbl * 64 + t * 16 + (ln & 15);
        int col = half * 32 + (ln >> 4) * 8;
        size_t ofs = (size_t)bh * 65536 + (size_t)(kb0 + kbl) * 4096 + f * 512 + ln * 8;
        *(uint4*)(gk + ofs) = *(uint4*)&lbuf[row][col];
    }
    __syncthreads();

    // ---- V path: kappa-permuted into lvt, then fragment-major store ----
    __bf16 (*lvt)[136] = (__bf16(*)[136])&lbuf[0][0];
    #pragma unroll
    for (int et = 0; et < 4; et++) {
        bf16x8 wf0 = *(const bf16x8*)&lw[1][et * 2 + 0][lane][0];
        bf16x8 wf1 = *(const bf16x8*)&lw[1][et * 2 + 1][lane][0];
        const float bias = lb[1][et * 16 + m];
        #pragma unroll
        for (int g = 0; g < 2; g++) {
            f32x4 acc = {0.f, 0.f, 0.f, 0.f};
            acc = MFMA(xf[g][0], wf0, acc);
            acc = MFMA(xf[g][1], wf1, acc);
            const int tp = (2 * w + g) & 3;
            const int p0 = 64 * (w >> 1) + 32 * (tp >> 1) + 8 * quad + 4 * (tp & 1);
            *(unsigned long long*)&lvt[et * 16 + m][p0] =
                pack4bf(acc[0] + bias, acc[1] + bias, acc[2] + bias, acc[3] + bias);
        }
    }
    __syncthreads();
    #pragma unroll
    for (int it = 0; it < 4; it++) {
        int c = it * 256 + tid;                       // chunk in [0,1024)
        int kbl = c >> 9, f = (c >> 6) & 7, ln = c & 63;
        int n = f >> 1, half = f & 1;
        int row = n * 16 + (ln & 15);                 // d index
        int col = kbl * 64 + half * 32 + (ln >> 4) * 8;   // local kappa col
        size_t ofs = (size_t)bh * 65536 + (size_t)(kb0 + kbl) * 4096 + f * 512 + ln * 8;
        *(uint4*)(gvt + ofs) = *(uint4*)&lvt[row][col];
    }
}

// ---------------------------------------------------------------------------
// Kernel 1: Q-proj prologue + flash attention + fused output projection.
// Grid (192 bh, 4 qb) x 512 threads (8 waves, 32 q-rows each).
// Main loop: fragment-major K/V loads (1KB contiguous per instr, L2-hot),
// ZERO LDS / barriers / bank conflicts.
// ---------------------------------------------------------------------------
__global__ __launch_bounds__(512, 4) void attn(
    const float* __restrict__ x,
    const float* __restrict__ Wq, const float* __restrict__ bq,
    const __bf16* __restrict__ gk, const __bf16* __restrict__ gvt,
    const float* __restrict__ Wo, const float* __restrict__ bo,
    float* __restrict__ out)
{
    __shared__ __align__(16) __bf16 xq[256][PAD];   // prologue only

    const int tid = threadIdx.x;
    const int w = tid >> 6, lane = tid & 63, m = lane & 15, quad = lane >> 4;
    const int bh = blockIdx.x;
    const int q0 = blockIdx.y * 256 + w * 32;

    // ---- prologue: stage my 256 x-rows fp32 -> bf16 ----
    const float* xq32 = x + ((size_t)bh * 1024 + blockIdx.y * 256) * 64;
    #pragma unroll
    for (int i = tid * 4; i < 16384; i += 2048) {
        float4 v = *(const float4*)(xq32 + i);
        int r = i >> 6, c = i & 63;
        *(unsigned long long*)&xq[r][c] = pack4bf(v.x, v.y, v.z, v.w);
    }
    __syncthreads();

    // Q-proj: this wave's 32 rows only (wave-private reads/writes)
    bf16x8 xqf[2][2];
    #pragma unroll
    for (int g = 0; g < 2; g++) {
        xqf[g][0] = *(const bf16x8*)&xq[w * 32 + g * 16 + m][quad * 8];
        xqf[g][1] = *(const bf16x8*)&xq[w * 32 + g * 16 + m][32 + quad * 8];
    }
    #pragma unroll
    for (int et = 0; et < 4; et++) {
        const float* wqrow = Wq + (size_t)(et * 16 + m) * 64;
        float4 a0 = *(const float4*)(wqrow + quad * 8);
        float4 a1 = *(const float4*)(wqrow + quad * 8 + 4);
        float4 a2 = *(const float4*)(wqrow + 32 + quad * 8);
        float4 a3 = *(const float4*)(wqrow + 36 + quad * 8);
        frag_u wf0, wf1;
        wf0.u[0] = pack4bf(a0.x, a0.y, a0.z, a0.w);
        wf0.u[1] = pack4bf(a1.x, a1.y, a1.z, a1.w);
        wf1.u[0] = pack4bf(a2.x, a2.y, a2.z, a2.w);
        wf1.u[1] = pack4bf(a3.x, a3.y, a3.z, a3.w);
        float4 bias = *(const float4*)(bq + et * 16 + quad * 4);
        #pragma unroll
        for (int g = 0; g < 2; g++) {
            f32x4 acc = {0.f, 0.f, 0.f, 0.f};
            acc = MFMA(wf0.v, xqf[g][0], acc);
            acc = MFMA(wf1.v, xqf[g][1], acc);
            *(unsigned long long*)&xq[w * 32 + g * 16 + m][et * 16 + quad * 4] =
                pack4bf((acc[0] + bias.x) * QSCALE, (acc[1] + bias.y) * QSCALE,
                        (acc[2] + bias.z) * QSCALE, (acc[3] + bias.w) * QSCALE);
        }
    }
    bf16x8 qf[2][2];
    #pragma unroll
    for (int g = 0; g < 2; g++) {
        qf[g][0] = *(const bf16x8*)&xq[w * 32 + g * 16 + m][quad * 8];
        qf[g][1] = *(const bf16x8*)&xq[w * 32 + g * 16 + m][32 + quad * 8];
    }
    // no further barriers: main loop touches no LDS.

    f32x4 o[2][4];
    float lsum[2] = {0.f, 0.f};
    #pragma unroll
    for (int g = 0; g < 2; g++)
        #pragma unroll
        for (int n = 0; n < 4; n++) o[g][n] = {0.f, 0.f, 0.f, 0.f};

    const __bf16* kfrag = gk + (size_t)bh * 65536 + lane * 8;
    const __bf16* vfrag = gvt + (size_t)bh * 65536 + lane * 8;

    for (int kb = 0; kb < 16; kb++) {
        // ---- all 16 fragment loads issued up front (each: 1KB contiguous) ----
        bf16x8 ka[4][2], va[4][2];
        #pragma unroll
        for (int f = 0; f < 8; f++)
            ka[f >> 1][f & 1] = *(const bf16x8*)(kfrag + (size_t)kb * 4096 + f * 512);
        #pragma unroll
        for (int f = 0; f < 8; f++)
            va[f >> 1][f & 1] = *(const bf16x8*)(vfrag + (size_t)kb * 4096 + f * 512);

        // ---- QK -> exp2 -> pack P^T straight into B-fragments ----
        __builtin_amdgcn_s_setprio(1);
        frag_u pb[2][2];
        #pragma unroll
        for (int t = 0; t < 4; t++) {
            #pragma unroll
            for (int g = 0; g < 2; g++) {
                f32x4 acc = {0.f, 0.f, 0.f, 0.f};
                acc = MFMA(ka[t][0], qf[g][0], acc);
                acc = MFMA(ka[t][1], qf[g][1], acc);
                float e0 = __builtin_amdgcn_exp2f(acc[0]);
                float e1 = __builtin_amdgcn_exp2f(acc[1]);
                float e2 = __builtin_amdgcn_exp2f(acc[2]);
                float e3 = __builtin_amdgcn_exp2f(acc[3]);
                lsum[g] += (e0 + e1) + (e2 + e3);
                pb[g][t >> 1].u[t & 1] = pack4bf(e0, e1, e2, e3);
            }
        }
        // ---- PV: O^T[d][q] += Vt_frag (A) * P^T-regs (B) ----
        #pragma unroll
        for (int n = 0; n < 4; n++) {
            #pragma unroll
            for (int g = 0; g < 2; g++) {
                o[g][n] = MFMA(va[n][0], pb[g][0].v, o[g][n]);
                o[g][n] = MFMA(va[n][1], pb[g][1].v, o[g][n]);
            }
        }
        __builtin_amdgcn_s_setprio(0);
    }

    // ---- epilogue: l reduce, O^T regs -> A-fragments, fused @ Wo + bo ----
    #pragma unroll
    for (int g = 0; g < 2; g++) {
        lsum[g] += __shfl_xor(lsum[g], 16);
        lsum[g] += __shfl_xor(lsum[g], 32);
    }

    // Wo fragments built inline from fp32 with kappa folded into addresses:
    bf16x8 wf[4][2];
    #pragma unroll
    for (int et = 0; et < 4; et++) {
        const float* worow = Wo + (size_t)(et * 16 + m) * 64;
        float4 c0 = *(const float4*)(worow + 4 * quad);
        float4 c1 = *(const float4*)(worow + 16 + 4 * quad);
        float4 c2 = *(const float4*)(worow + 32 + 4 * quad);
        float4 c3 = *(const float4*)(worow + 48 + 4 * quad);
        frag_u f0, f1;
        f0.u[0] = pack4bf(c0.x, c0.y, c0.z, c0.w);
        f0.u[1] = pack4bf(c1.x, c1.y, c1.z, c1.w);
        f1.u[0] = pack4bf(c2.x, c2.y, c2.z, c2.w);
        f1.u[1] = pack4bf(c3.x, c3.y, c3.z, c3.w);
        wf[et][0] = f0.v;
        wf[et][1] = f1.v;
    }
    float biasr[4];
    #pragma unroll
    for (int et = 0; et < 4; et++) biasr[et] = bo[et * 16 + m];

    #pragma unroll
    for (int g = 0; g < 2; g++) {
        const float inv = 1.f / lsum[g];
        frag_u af0, af1;
        af0.u[0] = pack4bf(o[g][0][0] * inv, o[g][0][1] * inv, o[g][0][2] * inv, o[g][0][3] * inv);
        af0.u[1] = pack4bf(o[g][1][0] * inv, o[g][1][1] * inv, o[g][1][2] * inv, o[g][1][3] * inv);
        af1.u[0] = pack4bf(o[g][2][0] * inv, o[g][2][1] * inv, o[g][2][2] * inv, o[g][2][3] * inv);
        af1.u[1] = pack4bf(o[g][3][0] * inv, o[g][3][1] * inv, o[g][3][2] * inv, o[g][3][3] * inv);
        #pragma unroll
        for (int et = 0; et < 4; et++) {
            f32x4 acc = {0.f, 0.f, 0.f, 0.f};
            acc = MFMA(af0.v, wf[et][0], acc);
            acc = MFMA(af1.v, wf[et][1], acc);
            #pragma unroll
            for (int r = 0; r < 4; r++) {
                size_t row = (size_t)bh * S + q0 + g * 16 + quad * 4 + r;
                out[row * 64 + et * 16 + m] = acc[r] + biasr[et];
            }
        }
    }
}

// ---------------------------------------------------------------------------
extern "C" void kernel_launch(void* const* d_in, const int* in_sizes, int n_in,
                              void* d_out, int out_size, void* d_ws, size_t ws_size,
                              hipStream_t stream) {
    const float* x  = (const float*)d_in[0];
    const float* Wq = (const float*)d_in[1];
    const float* bq = (const float*)d_in[2];
    const float* Wk = (const float*)d_in[3];
    const float* bk = (const float*)d_in[4];
    const float* Wv = (const float*)d_in[5];
    const float* bv = (const float*)d_in[6];
    const float* Wo = (const float*)d_in[7];
    const float* bo = (const float*)d_in[8];
    float* out = (float*)d_out;

    __bf16* gk  = (__bf16*)d_ws;
    __bf16* gvt = gk + NE;

    projkv<<<1536, 256, 0, stream>>>(x, Wk, bk, Wv, bv, gk, gvt);
    attn<<<dim3(192, 4), 512, 0, stream>>>(x, Wq, bq, gk, gvt, Wo, bo, out);
}

// Round 14
// 211.047 us; speedup vs baseline: 1.5023x; 1.0535x over previous
//
#include <hip/hip_runtime.h>
#include <math.h>

// B=16, H=12, S=1024, D=64.  BH=192, rows = B*H*S = 196608.
// R14: R13's fragment-major barrier-free loop, register-budgeted.
//   R13 post-mortem: conflicts 6.7M->0.39M (layout validated) but all-16-
//   loads-up-front made ka+va=64 live regs -> 4th spill (VGPR 64 + FETCH/WRITE
//   ballooned).  Fix: stage loads in QUARTERS -- K two t-tiles at a time in
//   the QK loop, V two n-tiles at a time in the PV loop; peak live ~85 unified
//   << 128 cap of (512,4).  All 8 waves/block read IDENTICAL fragment
//   addresses -> tiles are L1-broadcast; 16 decoupled waves/CU hide latency.
// ws layout (bf16): Kfrag[NE] | Vtfrag[NE]   (50.3 MB)
//   gk[bh][kb][f=t*2+half][lane][8], gvt[bh][kb][f=n*2+half][lane][8]
//
// KEY-PERMUTATION TRICK (unchanged): P^T exits QK in C-layout; reinterpreted
// as a B-fragment it supplies key kappa(s) at MFMA k-slot s.  Vt and Wo are
// stored/loaded pre-permuted by kappa so P and O feed MFMA from registers.
// kappa: s = 16t + 4q + r  ->  32*(t>>1) + 8*q + 4*(t&1) + r.

typedef __bf16 bf16x8 __attribute__((ext_vector_type(8)));
typedef float  f32x4  __attribute__((ext_vector_type(4)));

#define MFMA(a, b, c) __builtin_amdgcn_mfma_f32_16x16x32_bf16((a), (b), (c), 0, 0, 0)

static constexpr int S = 1024;
static constexpr int PAD = 72;      // 144 B row stride (proj + attn prologue LDS)
static constexpr size_t NE = 196608ull * 64ull;
// Q prescale: 1/sqrt(64) * log2(e)  -> scores arrive pre-scaled for exp2
static constexpr float QSCALE = 0.125f * 1.4426950408889634f;

__device__ inline unsigned long long pack4bf(float a, float b, float c, float d) {
    union { __bf16 h[4]; unsigned long long u; } pk;
    pk.h[0] = (__bf16)a; pk.h[1] = (__bf16)b; pk.h[2] = (__bf16)c; pk.h[3] = (__bf16)d;
    return pk.u;
}

union frag_u { bf16x8 v; unsigned long long u[2]; };

// ---------------------------------------------------------------------------
// Kernel 0: K/Vt projection, fragment-major stores (verbatim R13).
// LDS = lx 18.4K + lbuf 18.4K + lw 8K + lb 0.5K = 45.3 KB -> 3 blocks/CU.
// ---------------------------------------------------------------------------
__global__ __launch_bounds__(256, 3) void projkv(
    const float* __restrict__ x,
    const float* __restrict__ Wk, const float* __restrict__ bk,
    const float* __restrict__ Wv, const float* __restrict__ bv,
    __bf16* __restrict__ gk, __bf16* __restrict__ gvt)
{
    __shared__ __align__(16) __bf16 lx[128][PAD];
    __shared__ __align__(16) __bf16 lbuf[128][PAD];   // roundtrip; reused as [64][136] for Vt
    __shared__ __align__(16) __bf16 lw[2][8][64][8];
    __shared__ float lb[2][64];

    const int tid = threadIdx.x;
    const int row_base = blockIdx.x * 128;

    #pragma unroll
    for (int i = tid * 4; i < 8192; i += 1024) {
        float4 v = *(const float4*)(x + (size_t)row_base * 64 + i);
        int r = i >> 6, c = i & 63;
        *(unsigned long long*)&lx[r][c] = pack4bf(v.x, v.y, v.z, v.w);
    }
    #pragma unroll
    for (int c = tid; c < 1024; c += 256) {
        int mtx = c >> 9, rest = c & 511;
        int fe = rest >> 6, ln = rest & 63;
        int mm = ln & 15, qq = ln >> 4;
        int et = fe >> 1, half = fe & 1;
        const float* src = (mtx ? Wv : Wk) + (size_t)(et * 16 + mm) * 64 + half * 32 + qq * 8;
        float4 u0 = *(const float4*)(src);
        float4 u1 = *(const float4*)(src + 4);
        *(unsigned long long*)&lw[mtx][fe][ln][0] = pack4bf(u0.x, u0.y, u0.z, u0.w);
        *(unsigned long long*)&lw[mtx][fe][ln][4] = pack4bf(u1.x, u1.y, u1.z, u1.w);
    }
    if (tid < 64) { lb[0][tid] = bk[tid]; lb[1][tid] = bv[tid]; }
    __syncthreads();

    const int w = tid >> 6, lane = tid & 63, m = lane & 15, quad = lane >> 4;
    const int bh = row_base >> 10;
    const int s_base = row_base & 1023;
    const int kb0 = s_base >> 6;                      // first of 2 kb tiles

    bf16x8 xf[2][2];
    #pragma unroll
    for (int g = 0; g < 2; g++) {
        xf[g][0] = *(const bf16x8*)&lx[w * 32 + g * 16 + m][quad * 8];
        xf[g][1] = *(const bf16x8*)&lx[w * 32 + g * 16 + m][32 + quad * 8];
    }

    // ---- K: compute into lbuf (row-major), then fragment-major store ----
    #pragma unroll
    for (int et = 0; et < 4; et++) {
        bf16x8 wf0 = *(const bf16x8*)&lw[0][et * 2 + 0][lane][0];
        bf16x8 wf1 = *(const bf16x8*)&lw[0][et * 2 + 1][lane][0];
        float4 bias = *(const float4*)&lb[0][et * 16 + quad * 4];
        #pragma unroll
        for (int g = 0; g < 2; g++) {
            f32x4 acc = {0.f, 0.f, 0.f, 0.f};
            acc = MFMA(wf0, xf[g][0], acc);
            acc = MFMA(wf1, xf[g][1], acc);
            *(unsigned long long*)&lbuf[w * 32 + g * 16 + m][et * 16 + quad * 4] =
                pack4bf(acc[0] + bias.x, acc[1] + bias.y,
                        acc[2] + bias.z, acc[3] + bias.w);
        }
    }
    __syncthreads();
    #pragma unroll
    for (int it = 0; it < 4; it++) {
        int c = it * 256 + tid;                       // chunk in [0,1024)
        int kbl = c >> 9, f = (c >> 6) & 7, ln = c & 63;
        int t = f >> 1, half = f & 1;
        int row = kbl * 64 + t * 16 + (ln & 15);
        int col = half * 32 + (ln >> 4) * 8;
        size_t ofs = (size_t)bh * 65536 + (size_t)(kb0 + kbl) * 4096 + f * 512 + ln * 8;
        *(uint4*)(gk + ofs) = *(uint4*)&lbuf[row][col];
    }
    __syncthreads();

    // ---- V path: kappa-permuted into lvt, then fragment-major store ----
    __bf16 (*lvt)[136] = (__bf16(*)[136])&lbuf[0][0];
    #pragma unroll
    for (int et = 0; et < 4; et++) {
        bf16x8 wf0 = *(const bf16x8*)&lw[1][et * 2 + 0][lane][0];
        bf16x8 wf1 = *(const bf16x8*)&lw[1][et * 2 + 1][lane][0];
        const float bias = lb[1][et * 16 + m];
        #pragma unroll
        for (int g = 0; g < 2; g++) {
            f32x4 acc = {0.f, 0.f, 0.f, 0.f};
            acc = MFMA(xf[g][0], wf0, acc);
            acc = MFMA(xf[g][1], wf1, acc);
            const int tp = (2 * w + g) & 3;
            const int p0 = 64 * (w >> 1) + 32 * (tp >> 1) + 8 * quad + 4 * (tp & 1);
            *(unsigned long long*)&lvt[et * 16 + m][p0] =
                pack4bf(acc[0] + bias, acc[1] + bias, acc[2] + bias, acc[3] + bias);
        }
    }
    __syncthreads();
    #pragma unroll
    for (int it = 0; it < 4; it++) {
        int c = it * 256 + tid;                       // chunk in [0,1024)
        int kbl = c >> 9, f = (c >> 6) & 7, ln = c & 63;
        int n = f >> 1, half = f & 1;
        int row = n * 16 + (ln & 15);                 // d index
        int col = kbl * 64 + half * 32 + (ln >> 4) * 8;   // local kappa col
        size_t ofs = (size_t)bh * 65536 + (size_t)(kb0 + kbl) * 4096 + f * 512 + ln * 8;
        *(uint4*)(gvt + ofs) = *(uint4*)&lvt[row][col];
    }
}

// ---------------------------------------------------------------------------
// Kernel 1: Q-proj prologue + flash attention + fused output projection.
// Grid (192 bh, 4 qb) x 512 threads (8 waves, 32 q-rows each).
// Main loop: fragment-major K/V loads staged in QUARTERS (16 live regs max),
// no LDS / barriers / conflicts; all 8 waves read identical addresses.
// ---------------------------------------------------------------------------
__global__ __launch_bounds__(512, 4) void attn(
    const float* __restrict__ x,
    const float* __restrict__ Wq, const float* __restrict__ bq,
    const __bf16* __restrict__ gk, const __bf16* __restrict__ gvt,
    const float* __restrict__ Wo, const float* __restrict__ bo,
    float* __restrict__ out)
{
    __shared__ __align__(16) __bf16 xq[256][PAD];   // prologue only

    const int tid = threadIdx.x;
    const int w = tid >> 6, lane = tid & 63, m = lane & 15, quad = lane >> 4;
    const int bh = blockIdx.x;
    const int q0 = blockIdx.y * 256 + w * 32;

    // ---- prologue: stage my 256 x-rows fp32 -> bf16 ----
    const float* xq32 = x + ((size_t)bh * 1024 + blockIdx.y * 256) * 64;
    #pragma unroll
    for (int i = tid * 4; i < 16384; i += 2048) {
        float4 v = *(const float4*)(xq32 + i);
        int r = i >> 6, c = i & 63;
        *(unsigned long long*)&xq[r][c] = pack4bf(v.x, v.y, v.z, v.w);
    }
    __syncthreads();

    // Q-proj: this wave's 32 rows only (wave-private reads/writes)
    bf16x8 xqf[2][2];
    #pragma unroll
    for (int g = 0; g < 2; g++) {
        xqf[g][0] = *(const bf16x8*)&xq[w * 32 + g * 16 + m][quad * 8];
        xqf[g][1] = *(const bf16x8*)&xq[w * 32 + g * 16 + m][32 + quad * 8];
    }
    #pragma unroll
    for (int et = 0; et < 4; et++) {
        const float* wqrow = Wq + (size_t)(et * 16 + m) * 64;
        float4 a0 = *(const float4*)(wqrow + quad * 8);
        float4 a1 = *(const float4*)(wqrow + quad * 8 + 4);
        float4 a2 = *(const float4*)(wqrow + 32 + quad * 8);
        float4 a3 = *(const float4*)(wqrow + 36 + quad * 8);
        frag_u wf0, wf1;
        wf0.u[0] = pack4bf(a0.x, a0.y, a0.z, a0.w);
        wf0.u[1] = pack4bf(a1.x, a1.y, a1.z, a1.w);
        wf1.u[0] = pack4bf(a2.x, a2.y, a2.z, a2.w);
        wf1.u[1] = pack4bf(a3.x, a3.y, a3.z, a3.w);
        float4 bias = *(const float4*)(bq + et * 16 + quad * 4);
        #pragma unroll
        for (int g = 0; g < 2; g++) {
            f32x4 acc = {0.f, 0.f, 0.f, 0.f};
            acc = MFMA(wf0.v, xqf[g][0], acc);
            acc = MFMA(wf1.v, xqf[g][1], acc);
            *(unsigned long long*)&xq[w * 32 + g * 16 + m][et * 16 + quad * 4] =
                pack4bf((acc[0] + bias.x) * QSCALE, (acc[1] + bias.y) * QSCALE,
                        (acc[2] + bias.z) * QSCALE, (acc[3] + bias.w) * QSCALE);
        }
    }
    bf16x8 qf[2][2];
    #pragma unroll
    for (int g = 0; g < 2; g++) {
        qf[g][0] = *(const bf16x8*)&xq[w * 32 + g * 16 + m][quad * 8];
        qf[g][1] = *(const bf16x8*)&xq[w * 32 + g * 16 + m][32 + quad * 8];
    }
    // no further barriers: main loop touches no LDS.

    f32x4 o[2][4];
    float lsum[2] = {0.f, 0.f};
    #pragma unroll
    for (int g = 0; g < 2; g++)
        #pragma unroll
        for (int n = 0; n < 4; n++) o[g][n] = {0.f, 0.f, 0.f, 0.f};

    const __bf16* kfrag = gk + (size_t)bh * 65536 + lane * 8;
    const __bf16* vfrag = gvt + (size_t)bh * 65536 + lane * 8;

    for (int kb = 0; kb < 16; kb++) {
        frag_u pb[2][2];
        // ---- QK: K fragments in two t-pairs (16 live regs each) ----
        #pragma unroll
        for (int th = 0; th < 2; th++) {
            bf16x8 ka[2][2];
            #pragma unroll
            for (int f2 = 0; f2 < 4; f2++) {
                const int f = th * 4 + f2;
                ka[f2 >> 1][f2 & 1] = *(const bf16x8*)(kfrag + (size_t)kb * 4096 + f * 512);
            }
            __builtin_amdgcn_s_setprio(1);
            #pragma unroll
            for (int t2 = 0; t2 < 2; t2++) {
                const int t = th * 2 + t2;
                #pragma unroll
                for (int g = 0; g < 2; g++) {
                    f32x4 acc = {0.f, 0.f, 0.f, 0.f};
                    acc = MFMA(ka[t2][0], qf[g][0], acc);
                    acc = MFMA(ka[t2][1], qf[g][1], acc);
                    float e0 = __builtin_amdgcn_exp2f(acc[0]);
                    float e1 = __builtin_amdgcn_exp2f(acc[1]);
                    float e2 = __builtin_amdgcn_exp2f(acc[2]);
                    float e3 = __builtin_amdgcn_exp2f(acc[3]);
                    lsum[g] += (e0 + e1) + (e2 + e3);
                    pb[g][t >> 1].u[t & 1] = pack4bf(e0, e1, e2, e3);
                }
            }
            __builtin_amdgcn_s_setprio(0);
        }
        // ---- PV: V fragments in two n-pairs (16 live regs each) ----
        #pragma unroll
        for (int nh = 0; nh < 2; nh++) {
            bf16x8 va[2][2];
            #pragma unroll
            for (int f2 = 0; f2 < 4; f2++) {
                const int f = nh * 4 + f2;
                va[f2 >> 1][f2 & 1] = *(const bf16x8*)(vfrag + (size_t)kb * 4096 + f * 512);
            }
            __builtin_amdgcn_s_setprio(1);
            #pragma unroll
            for (int n2 = 0; n2 < 2; n2++) {
                const int n = nh * 2 + n2;
                #pragma unroll
                for (int g = 0; g < 2; g++) {
                    o[g][n] = MFMA(va[n2][0], pb[g][0].v, o[g][n]);
                    o[g][n] = MFMA(va[n2][1], pb[g][1].v, o[g][n]);
                }
            }
            __builtin_amdgcn_s_setprio(0);
        }
    }

    // ---- epilogue: l reduce, O^T regs -> A-fragments, fused @ Wo + bo ----
    #pragma unroll
    for (int g = 0; g < 2; g++) {
        lsum[g] += __shfl_xor(lsum[g], 16);
        lsum[g] += __shfl_xor(lsum[g], 32);
    }

    // Wo fragments built inline from fp32 with kappa folded into addresses:
    bf16x8 wf[4][2];
    #pragma unroll
    for (int et = 0; et < 4; et++) {
        const float* worow = Wo + (size_t)(et * 16 + m) * 64;
        float4 c0 = *(const float4*)(worow + 4 * quad);
        float4 c1 = *(const float4*)(worow + 16 + 4 * quad);
        float4 c2 = *(const float4*)(worow + 32 + 4 * quad);
        float4 c3 = *(const float4*)(worow + 48 + 4 * quad);
        frag_u f0, f1;
        f0.u[0] = pack4bf(c0.x, c0.y, c0.z, c0.w);
        f0.u[1] = pack4bf(c1.x, c1.y, c1.z, c1.w);
        f1.u[0] = pack4bf(c2.x, c2.y, c2.z, c2.w);
        f1.u[1] = pack4bf(c3.x, c3.y, c3.z, c3.w);
        wf[et][0] = f0.v;
        wf[et][1] = f1.v;
    }
    float biasr[4];
    #pragma unroll
    for (int et = 0; et < 4; et++) biasr[et] = bo[et * 16 + m];

    #pragma unroll
    for (int g = 0; g < 2; g++) {
        const float inv = 1.f / lsum[g];
        frag_u af0, af1;
        af0.u[0] = pack4bf(o[g][0][0] * inv, o[g][0][1] * inv, o[g][0][2] * inv, o[g][0][3] * inv);
        af0.u[1] = pack4bf(o[g][1][0] * inv, o[g][1][1] * inv, o[g][1][2] * inv, o[g][1][3] * inv);
        af1.u[0] = pack4bf(o[g][2][0] * inv, o[g][2][1] * inv, o[g][2][2] * inv, o[g][2][3] * inv);
        af1.u[1] = pack4bf(o[g][3][0] * inv, o[g][3][1] * inv, o[g][3][2] * inv, o[g][3][3] * inv);
        #pragma unroll
        for (int et = 0; et < 4; et++) {
            f32x4 acc = {0.f, 0.f, 0.f, 0.f};
            acc = MFMA(af0.v, wf[et][0], acc);
            acc = MFMA(af1.v, wf[et][1], acc);
            #pragma unroll
            for (int r = 0; r < 4; r++) {
                size_t row = (size_t)bh * S + q0 + g * 16 + quad * 4 + r;
                out[row * 64 + et * 16 + m] = acc[r] + biasr[et];
            }
        }
    }
}

// ---------------------------------------------------------------------------
extern "C" void kernel_launch(void* const* d_in, const int* in_sizes, int n_in,
                              void* d_out, int out_size, void* d_ws, size_t ws_size,
                              hipStream_t stream) {
    const float* x  = (const float*)d_in[0];
    const float* Wq = (const float*)d_in[1];
    const float* bq = (const float*)d_in[2];
    const float* Wk = (const float*)d_in[3];
    const float* bk = (const float*)d_in[4];
    const float* Wv = (const float*)d_in[5];
    const float* bv = (const float*)d_in[6];
    const float* Wo = (const float*)d_in[7];
    const float* bo = (const float*)d_in[8];
    float* out = (float*)d_out;

    __bf16* gk  = (__bf16*)d_ws;
    __bf16* gvt = gk + NE;

    projkv<<<1536, 256, 0, stream>>>(x, Wk, bk, Wv, bv, gk, gvt);
    attn<<<dim3(192, 4), 512, 0, stream>>>(x, Wq, bq, gk, gvt, Wo, bo, out);
}

// Round 15
// 198.317 us; speedup vs baseline: 1.5987x; 1.0642x over previous
//
#include <hip/hip_runtime.h>
#include <math.h>

// B=16, H=12, S=1024, D=64.  BH=192, rows = B*H*S = 196608.
// R15: R11 + cross-tile QK/PV software pipeline (T15) with triple-buffered LDS.
//   Ledger: every clean variant (LDS or direct, 1-3 barriers, conflicts or
//   none, occ 15-35%) lands 97-116us with MfmaUtil<28 / VALU<52 / HBM<18%.
//   The invariant is the per-tile chain QK-MFMA -> exp2(32 trans/kb) -> pack
//   -> PV-MFMA: pipes mutually serialized, waves convoy.
//   Fix: interleave PV(kb-1) (independent of QK(kb)'s chain, feeds the MFMA
//   pipe during exp2) with QK(kb).  Needs tiles kb-1,kb live while staging
//   kb+1 -> k/v[3] triple buffer (55.3KB, 2 blocks/CU at (512,4)), ONE
//   barrier per kb (18 total).  Tile accumulation order unchanged -> bitwise
//   identical results.  projkv verbatim R11.
// ws layout (bf16): K[NE] | Vt_perm[NE]   (50.3 MB)
//
// KEY-PERMUTATION TRICK (unchanged): P^T exits QK in C-layout; reinterpreted
// as a B-fragment it supplies key kappa(s) at MFMA k-slot s.  Vt and Wo are
// stored/loaded pre-permuted by kappa so P and O feed MFMA from registers.
// kappa: s = 16t + 4q + r  ->  32*(t>>1) + 8*q + 4*(t&1) + r.

typedef __bf16 bf16x8 __attribute__((ext_vector_type(8)));
typedef float  f32x4  __attribute__((ext_vector_type(4)));

#define MFMA(a, b, c) __builtin_amdgcn_mfma_f32_16x16x32_bf16((a), (b), (c), 0, 0, 0)

static constexpr int S = 1024;
static constexpr int PAD = 72;      // 144 B row stride: 16B-aligned, breaks 128B aliasing
static constexpr size_t NE = 196608ull * 64ull;
// Q prescale: 1/sqrt(64) * log2(e)  -> scores arrive pre-scaled for exp2
static constexpr float QSCALE = 0.125f * 1.4426950408889634f;

__device__ inline unsigned long long pack4bf(float a, float b, float c, float d) {
    union { __bf16 h[4]; unsigned long long u; } pk;
    pk.h[0] = (__bf16)a; pk.h[1] = (__bf16)b; pk.h[2] = (__bf16)c; pk.h[3] = (__bf16)d;
    return pk.u;
}

union frag_u { bf16x8 v; unsigned long long u[2]; };

// ---------------------------------------------------------------------------
// Kernel 0: K/Vt projection (verbatim R11).  K row-major; Vt [bh][d][key-kappa].
// LDS = lx 18.4K + lbuf 18.4K + lw 8K + lb 0.5K = 45.3 KB -> 3 blocks/CU.
// ---------------------------------------------------------------------------
__global__ __launch_bounds__(256, 3) void projkv(
    const float* __restrict__ x,
    const float* __restrict__ Wk, const float* __restrict__ bk,
    const float* __restrict__ Wv, const float* __restrict__ bv,
    __bf16* __restrict__ gk, __bf16* __restrict__ gvt)
{
    __shared__ __align__(16) __bf16 lx[128][PAD];
    __shared__ __align__(16) __bf16 lbuf[128][PAD];   // roundtrip; reused as [64][136] for Vt
    __shared__ __align__(16) __bf16 lw[2][8][64][8];
    __shared__ float lb[2][64];

    const int tid = threadIdx.x;
    const int row_base = blockIdx.x * 128;

    #pragma unroll
    for (int i = tid * 4; i < 8192; i += 1024) {
        float4 v = *(const float4*)(x + (size_t)row_base * 64 + i);
        int r = i >> 6, c = i & 63;
        *(unsigned long long*)&lx[r][c] = pack4bf(v.x, v.y, v.z, v.w);
    }
    #pragma unroll
    for (int c = tid; c < 1024; c += 256) {
        int mtx = c >> 9, rest = c & 511;
        int fe = rest >> 6, ln = rest & 63;
        int mm = ln & 15, qq = ln >> 4;
        int et = fe >> 1, half = fe & 1;
        const float* src = (mtx ? Wv : Wk) + (size_t)(et * 16 + mm) * 64 + half * 32 + qq * 8;
        float4 u0 = *(const float4*)(src);
        float4 u1 = *(const float4*)(src + 4);
        *(unsigned long long*)&lw[mtx][fe][ln][0] = pack4bf(u0.x, u0.y, u0.z, u0.w);
        *(unsigned long long*)&lw[mtx][fe][ln][4] = pack4bf(u1.x, u1.y, u1.z, u1.w);
    }
    if (tid < 64) { lb[0][tid] = bk[tid]; lb[1][tid] = bv[tid]; }
    __syncthreads();

    const int w = tid >> 6, lane = tid & 63, m = lane & 15, quad = lane >> 4;
    const int bh = row_base >> 10;
    const int s_base = row_base & 1023;

    bf16x8 xf[2][2];
    #pragma unroll
    for (int g = 0; g < 2; g++) {
        xf[g][0] = *(const bf16x8*)&lx[w * 32 + g * 16 + m][quad * 8];
        xf[g][1] = *(const bf16x8*)&lx[w * 32 + g * 16 + m][32 + quad * 8];
    }

    // ---- K: compute, roundtrip, coalesced store ----
    #pragma unroll
    for (int et = 0; et < 4; et++) {
        bf16x8 wf0 = *(const bf16x8*)&lw[0][et * 2 + 0][lane][0];
        bf16x8 wf1 = *(const bf16x8*)&lw[0][et * 2 + 1][lane][0];
        float4 bias = *(const float4*)&lb[0][et * 16 + quad * 4];
        #pragma unroll
        for (int g = 0; g < 2; g++) {
            f32x4 acc = {0.f, 0.f, 0.f, 0.f};
            acc = MFMA(wf0, xf[g][0], acc);
            acc = MFMA(wf1, xf[g][1], acc);
            *(unsigned long long*)&lbuf[w * 32 + g * 16 + m][et * 16 + quad * 4] =
                pack4bf(acc[0] + bias.x, acc[1] + bias.y,
                        acc[2] + bias.z, acc[3] + bias.w);
        }
    }
    __syncthreads();
    #pragma unroll
    for (int it = 0; it < 4; it++) {
        int idx = it * 256 + tid;
        int row = idx >> 3, col = (idx & 7) * 8;
        *(uint4*)(gk + ((size_t)row_base + row) * 64 + col) = *(uint4*)&lbuf[row][col];
    }
    __syncthreads();

    // ---- V path: rows s_local = w*32+g*16+quad*4+r -> kappa-permuted pos ----
    __bf16 (*lvt)[136] = (__bf16(*)[136])&lbuf[0][0];
    #pragma unroll
    for (int et = 0; et < 4; et++) {
        bf16x8 wf0 = *(const bf16x8*)&lw[1][et * 2 + 0][lane][0];
        bf16x8 wf1 = *(const bf16x8*)&lw[1][et * 2 + 1][lane][0];
        const float bias = lb[1][et * 16 + m];
        #pragma unroll
        for (int g = 0; g < 2; g++) {
            f32x4 acc = {0.f, 0.f, 0.f, 0.f};
            acc = MFMA(xf[g][0], wf0, acc);
            acc = MFMA(xf[g][1], wf1, acc);
            const int tp = (2 * w + g) & 3;
            const int p0 = 64 * (w >> 1) + 32 * (tp >> 1) + 8 * quad + 4 * (tp & 1);
            *(unsigned long long*)&lvt[et * 16 + m][p0] =
                pack4bf(acc[0] + bias, acc[1] + bias, acc[2] + bias, acc[3] + bias);
        }
    }
    __syncthreads();
    #pragma unroll
    for (int it = 0; it < 4; it++) {
        int idx = it * 256 + tid;
        int row = idx >> 4, col = (idx & 15) * 8;
        *(uint4*)(gvt + ((size_t)bh * 64 + row) * 1024 + s_base + col) = *(uint4*)&lvt[row][col];
    }
}

// ---------------------------------------------------------------------------
// Kernel 1: Q-proj prologue + pipelined flash attention + fused out-proj.
// Grid (192 bh, 4 qb) x 512 threads (8 waves, 32 q-rows each).
// Main loop: ONE barrier per kb; PV(kb-1) interleaved with QK(kb); K/V in a
// 3-deep LDS ring; tile kb+1 staged from regs right after the barrier.
// ---------------------------------------------------------------------------
__global__ __launch_bounds__(512, 4) void attn(
    const float* __restrict__ x,
    const float* __restrict__ Wq, const float* __restrict__ bq,
    const __bf16* __restrict__ gk, const __bf16* __restrict__ gvt,
    const float* __restrict__ Wo, const float* __restrict__ bo,
    float* __restrict__ out)
{
    __shared__ __align__(16) union {
        __bf16 xq[256][PAD];            // prologue: x (q rows), then Q roundtrip
        struct {
            __bf16 k[3][64][PAD];       // K tiles, 3-deep ring
            __bf16 v[3][64][PAD];       // Vt tiles, 3-deep ring
        } m;
    } L;

    const int tid = threadIdx.x;
    const int w = tid >> 6, lane = tid & 63, m = lane & 15, quad = lane >> 4;
    const int bh = blockIdx.x;
    const int q0 = blockIdx.y * 256 + w * 32;

    // ---- prologue: stage my 256 x-rows fp32 -> bf16 ----
    const float* xq32 = x + ((size_t)bh * 1024 + blockIdx.y * 256) * 64;
    #pragma unroll
    for (int i = tid * 4; i < 16384; i += 2048) {
        float4 v = *(const float4*)(xq32 + i);
        int r = i >> 6, c = i & 63;
        *(unsigned long long*)&L.xq[r][c] = pack4bf(v.x, v.y, v.z, v.w);
    }
    __syncthreads();

    // Q-proj: this wave's 32 rows only (wave-private reads/writes)
    bf16x8 xqf[2][2];
    #pragma unroll
    for (int g = 0; g < 2; g++) {
        xqf[g][0] = *(const bf16x8*)&L.xq[w * 32 + g * 16 + m][quad * 8];
        xqf[g][1] = *(const bf16x8*)&L.xq[w * 32 + g * 16 + m][32 + quad * 8];
    }
    #pragma unroll
    for (int et = 0; et < 4; et++) {
        const float* wqrow = Wq + (size_t)(et * 16 + m) * 64;
        float4 a0 = *(const float4*)(wqrow + quad * 8);
        float4 a1 = *(const float4*)(wqrow + quad * 8 + 4);
        float4 a2 = *(const float4*)(wqrow + 32 + quad * 8);
        float4 a3 = *(const float4*)(wqrow + 36 + quad * 8);
        frag_u wf0, wf1;
        wf0.u[0] = pack4bf(a0.x, a0.y, a0.z, a0.w);
        wf0.u[1] = pack4bf(a1.x, a1.y, a1.z, a1.w);
        wf1.u[0] = pack4bf(a2.x, a2.y, a2.z, a2.w);
        wf1.u[1] = pack4bf(a3.x, a3.y, a3.z, a3.w);
        float4 bias = *(const float4*)(bq + et * 16 + quad * 4);
        #pragma unroll
        for (int g = 0; g < 2; g++) {
            f32x4 acc = {0.f, 0.f, 0.f, 0.f};
            acc = MFMA(wf0.v, xqf[g][0], acc);
            acc = MFMA(wf1.v, xqf[g][1], acc);
            *(unsigned long long*)&L.xq[w * 32 + g * 16 + m][et * 16 + quad * 4] =
                pack4bf((acc[0] + bias.x) * QSCALE, (acc[1] + bias.y) * QSCALE,
                        (acc[2] + bias.z) * QSCALE, (acc[3] + bias.w) * QSCALE);
        }
    }
    bf16x8 qf[2][2];
    #pragma unroll
    for (int g = 0; g < 2; g++) {
        qf[g][0] = *(const bf16x8*)&L.xq[w * 32 + g * 16 + m][quad * 8];
        qf[g][1] = *(const bf16x8*)&L.xq[w * 32 + g * 16 + m][32 + quad * 8];
    }

    const int sr = tid >> 3;            // 0..63 (512 threads)
    const int sc = (tid & 7) * 8;       // 16B chunk col
    const __bf16* kbase = gk + (size_t)bh * S * 64;
    const __bf16* vbase = gvt + (size_t)bh * 64 * 1024;

    // prefetch tile 0 (global loads; legal before the barrier)
    uint4 kreg = *(const uint4*)(kbase + (size_t)sr * 64 + sc);
    uint4 vreg = *(const uint4*)(vbase + (size_t)sr * 1024 + sc);

    __syncthreads();                    // xq reads done -> ring area free

    f32x4 o[2][4];
    float lsum[2] = {0.f, 0.f};
    #pragma unroll
    for (int g = 0; g < 2; g++)
        #pragma unroll
        for (int n = 0; n < 4; n++) o[g][n] = {0.f, 0.f, 0.f, 0.f};

    // stage tile 0 -> buf0; prefetch tile 1
    *(uint4*)&L.m.k[0][sr][sc] = kreg;
    *(uint4*)&L.m.v[0][sr][sc] = vreg;
    kreg = *(const uint4*)(kbase + (size_t)(64 + sr) * 64 + sc);
    vreg = *(const uint4*)(vbase + (size_t)sr * 1024 + 64 + sc);
    __syncthreads();                    // buf0 published

    // stage tile 1 -> buf1 (disjoint from buf0 readers); prefetch tile 2
    *(uint4*)&L.m.k[1][sr][sc] = kreg;
    *(uint4*)&L.m.v[1][sr][sc] = vreg;
    kreg = *(const uint4*)(kbase + (size_t)(128 + sr) * 64 + sc);
    vreg = *(const uint4*)(vbase + (size_t)sr * 1024 + 128 + sc);

    // ---- QK(0) -> pb (no PV yet) ----
    frag_u pb[2][2];
    __builtin_amdgcn_s_setprio(1);
    #pragma unroll
    for (int tn = 0; tn < 4; tn++) {
        bf16x8 ka0 = *(const bf16x8*)&L.m.k[0][tn * 16 + m][quad * 8];
        bf16x8 ka1 = *(const bf16x8*)&L.m.k[0][tn * 16 + m][32 + quad * 8];
        #pragma unroll
        for (int g = 0; g < 2; g++) {
            f32x4 acc = {0.f, 0.f, 0.f, 0.f};
            acc = MFMA(ka0, qf[g][0], acc);
            acc = MFMA(ka1, qf[g][1], acc);
            float e0 = __builtin_amdgcn_exp2f(acc[0]);
            float e1 = __builtin_amdgcn_exp2f(acc[1]);
            float e2 = __builtin_amdgcn_exp2f(acc[2]);
            float e3 = __builtin_amdgcn_exp2f(acc[3]);
            lsum[g] += (e0 + e1) + (e2 + e3);
            pb[g][tn >> 1].u[tn & 1] = pack4bf(e0, e1, e2, e3);
        }
    }
    __builtin_amdgcn_s_setprio(0);

    // ---- main loop kb = 1..14: stage kb+1, QK(kb) ∥ PV(kb-1) ----
    int cur = 1, prv = 0, nxt = 2;      // ring indices (kb % 3 etc.)
    for (int kb = 1; kb < 15; kb++) {
        __syncthreads();                // buf[cur] published; buf[nxt] readers done
        *(uint4*)&L.m.k[nxt][sr][sc] = kreg;
        *(uint4*)&L.m.v[nxt][sr][sc] = vreg;
        if (kb < 14) {
            const int nb = (kb + 2) * 64;
            kreg = *(const uint4*)(kbase + (size_t)(nb + sr) * 64 + sc);
            vreg = *(const uint4*)(vbase + (size_t)sr * 1024 + nb + sc);
        }

        __builtin_amdgcn_s_setprio(1);
        frag_u pbn[2][2];
        #pragma unroll
        for (int tn = 0; tn < 4; tn++) {
            bf16x8 ka0 = *(const bf16x8*)&L.m.k[cur][tn * 16 + m][quad * 8];
            bf16x8 ka1 = *(const bf16x8*)&L.m.k[cur][tn * 16 + m][32 + quad * 8];
            bf16x8 va0 = *(const bf16x8*)&L.m.v[prv][tn * 16 + m][quad * 8];
            bf16x8 va1 = *(const bf16x8*)&L.m.v[prv][tn * 16 + m][32 + quad * 8];
            // PV(kb-1): independent of this tile's QK chain -> fills MFMA pipe
            #pragma unroll
            for (int g = 0; g < 2; g++) {
                o[g][tn] = MFMA(va0, pb[g][0].v, o[g][tn]);
                o[g][tn] = MFMA(va1, pb[g][1].v, o[g][tn]);
            }
            // QK(kb) -> exp2 -> pack
            #pragma unroll
            for (int g = 0; g < 2; g++) {
                f32x4 acc = {0.f, 0.f, 0.f, 0.f};
                acc = MFMA(ka0, qf[g][0], acc);
                acc = MFMA(ka1, qf[g][1], acc);
                float e0 = __builtin_amdgcn_exp2f(acc[0]);
                float e1 = __builtin_amdgcn_exp2f(acc[1]);
                float e2 = __builtin_amdgcn_exp2f(acc[2]);
                float e3 = __builtin_amdgcn_exp2f(acc[3]);
                lsum[g] += (e0 + e1) + (e2 + e3);
                pbn[g][tn >> 1].u[tn & 1] = pack4bf(e0, e1, e2, e3);
            }
        }
        __builtin_amdgcn_s_setprio(0);
        #pragma unroll
        for (int g = 0; g < 2; g++)
            #pragma unroll
            for (int i = 0; i < 2; i++) {
                pb[g][i].u[0] = pbn[g][i].u[0];
                pb[g][i].u[1] = pbn[g][i].u[1];
            }
        int t = prv; prv = cur; cur = nxt; nxt = t;   // rotate ring
    }

    // ---- kb = 15 (peeled: no staging): QK(15) ∥ PV(14), then PV(15) ----
    __syncthreads();                    // buf[cur] (tile 15) published
    {
        __builtin_amdgcn_s_setprio(1);
        frag_u pbn[2][2];
        #pragma unroll
        for (int tn = 0; tn < 4; tn++) {
            bf16x8 ka0 = *(const bf16x8*)&L.m.k[cur][tn * 16 + m][quad * 8];
            bf16x8 ka1 = *(const bf16x8*)&L.m.k[cur][tn * 16 + m][32 + quad * 8];
            bf16x8 va0 = *(const bf16x8*)&L.m.v[prv][tn * 16 + m][quad * 8];
            bf16x8 va1 = *(const bf16x8*)&L.m.v[prv][tn * 16 + m][32 + quad * 8];
            #pragma unroll
            for (int g = 0; g < 2; g++) {
                o[g][tn] = MFMA(va0, pb[g][0].v, o[g][tn]);
                o[g][tn] = MFMA(va1, pb[g][1].v, o[g][tn]);
            }
            #pragma unroll
            for (int g = 0; g < 2; g++) {
                f32x4 acc = {0.f, 0.f, 0.f, 0.f};
                acc = MFMA(ka0, qf[g][0], acc);
                acc = MFMA(ka1, qf[g][1], acc);
                float e0 = __builtin_amdgcn_exp2f(acc[0]);
                float e1 = __builtin_amdgcn_exp2f(acc[1]);
                float e2 = __builtin_amdgcn_exp2f(acc[2]);
                float e3 = __builtin_amdgcn_exp2f(acc[3]);
                lsum[g] += (e0 + e1) + (e2 + e3);
                pbn[g][tn >> 1].u[tn & 1] = pack4bf(e0, e1, e2, e3);
            }
        }
        // PV(15) from buf[cur]'s V
        #pragma unroll
        for (int tn = 0; tn < 4; tn++) {
            bf16x8 va0 = *(const bf16x8*)&L.m.v[cur][tn * 16 + m][quad * 8];
            bf16x8 va1 = *(const bf16x8*)&L.m.v[cur][tn * 16 + m][32 + quad * 8];
            #pragma unroll
            for (int g = 0; g < 2; g++) {
                o[g][tn] = MFMA(va0, pbn[g][0].v, o[g][tn]);
                o[g][tn] = MFMA(va1, pbn[g][1].v, o[g][tn]);
            }
        }
        __builtin_amdgcn_s_setprio(0);
    }

    // ---- epilogue: l reduce, O^T regs -> A-fragments, fused @ Wo + bo ----
    #pragma unroll
    for (int g = 0; g < 2; g++) {
        lsum[g] += __shfl_xor(lsum[g], 16);
        lsum[g] += __shfl_xor(lsum[g], 32);
    }

    // Wo fragments built inline from fp32 with kappa folded into addresses:
    bf16x8 wf[4][2];
    #pragma unroll
    for (int et = 0; et < 4; et++) {
        const float* worow = Wo + (size_t)(et * 16 + m) * 64;
        float4 c0 = *(const float4*)(worow + 4 * quad);
        float4 c1 = *(const float4*)(worow + 16 + 4 * quad);
        float4 c2 = *(const float4*)(worow + 32 + 4 * quad);
        float4 c3 = *(const float4*)(worow + 48 + 4 * quad);
        frag_u f0, f1;
        f0.u[0] = pack4bf(c0.x, c0.y, c0.z, c0.w);
        f0.u[1] = pack4bf(c1.x, c1.y, c1.z, c1.w);
        f1.u[0] = pack4bf(c2.x, c2.y, c2.z, c2.w);
        f1.u[1] = pack4bf(c3.x, c3.y, c3.z, c3.w);
        wf[et][0] = f0.v;
        wf[et][1] = f1.v;
    }
    float biasr[4];
    #pragma unroll
    for (int et = 0; et < 4; et++) biasr[et] = bo[et * 16 + m];

    #pragma unroll
    for (int g = 0; g < 2; g++) {
        const float inv = 1.f / lsum[g];
        frag_u af0, af1;
        af0.u[0] = pack4bf(o[g][0][0] * inv, o[g][0][1] * inv, o[g][0][2] * inv, o[g][0][3] * inv);
        af0.u[1] = pack4bf(o[g][1][0] * inv, o[g][1][1] * inv, o[g][1][2] * inv, o[g][1][3] * inv);
        af1.u[0] = pack4bf(o[g][2][0] * inv, o[g][2][1] * inv, o[g][2][2] * inv, o[g][2][3] * inv);
        af1.u[1] = pack4bf(o[g][3][0] * inv, o[g][3][1] * inv, o[g][3][2] * inv, o[g][3][3] * inv);
        #pragma unroll
        for (int et = 0; et < 4; et++) {
            f32x4 acc = {0.f, 0.f, 0.f, 0.f};
            acc = MFMA(af0.v, wf[et][0], acc);
            acc = MFMA(af1.v, wf[et][1], acc);
            #pragma unroll
            for (int r = 0; r < 4; r++) {
                size_t row = (size_t)bh * S + q0 + g * 16 + quad * 4 + r;
                out[row * 64 + et * 16 + m] = acc[r] + biasr[et];
            }
        }
    }
}

// ---------------------------------------------------------------------------
extern "C" void kernel_launch(void* const* d_in, const int* in_sizes, int n_in,
                              void* d_out, int out_size, void* d_ws, size_t ws_size,
                              hipStream_t stream) {
    const float* x  = (const float*)d_in[0];
    const float* Wq = (const float*)d_in[1];
    const float* bq = (const float*)d_in[2];
    const float* Wk = (const float*)d_in[3];
    const float* bk = (const float*)d_in[4];
    const float* Wv = (const float*)d_in[5];
    const float* bv = (const float*)d_in[6];
    const float* Wo = (const float*)d_in[7];
    const float* bo = (const float*)d_in[8];
    float* out = (float*)d_out;

    __bf16* gk  = (__bf16*)d_ws;
    __bf16* gvt = gk + NE;

    projkv<<<1536, 256, 0, stream>>>(x, Wk, bk, Wv, bv, gk, gvt);
    attn<<<dim3(192, 4), 512, 0, stream>>>(x, Wq, bq, gk, gvt, Wo, bo, out);
}